// Round 5
// baseline (620.389 us; speedup 1.0000x reference)
//
#include <hip/hip_runtime.h>

typedef _Float16 half8  __attribute__((ext_vector_type(8)));
typedef float    f32x4  __attribute__((ext_vector_type(4)));
typedef int      i32x4  __attribute__((ext_vector_type(4)));

#define NB 2
#define N_C 16384
#define N_F 65536
#define E_C 65536
#define E_F 262144

// ---------------- fused clear: out=0, h_a=0, inv=-1, cnt=0 ----------------
#define OUT4  ((size_t)NB * N_F * 128 / 4)
#define HA4   ((size_t)NB * N_C * 64 / 4)
#define INV4  ((size_t)N_F / 4)
#define CNT4  ((size_t)(N_F + N_C) / 4)
#define CLR4  (OUT4 + HA4 + INV4 + CNT4)

__global__ void clear_all(float* __restrict__ out, float* __restrict__ h_a,
                          int* __restrict__ inv, int* __restrict__ cnt) {
    size_t i = (size_t)blockIdx.x * 256 + threadIdx.x;
    if (i >= CLR4) return;
    const i32x4 z = {0, 0, 0, 0};
    const i32x4 m1 = {-1, -1, -1, -1};
    if (i < OUT4) ((i32x4*)out)[i] = z;
    else if (i < OUT4 + HA4) ((i32x4*)h_a)[i - OUT4] = z;
    else if (i < OUT4 + HA4 + INV4) ((i32x4*)inv)[i - OUT4 - HA4] = m1;
    else ((i32x4*)cnt)[i - OUT4 - HA4 - INV4] = z;
}

// ---------------- fused setup: build_inv + 6 weight swizzles + 2 hists ----------------
__device__ inline void swizzle_dev(const float* __restrict__ W, _Float16* __restrict__ Ws,
                                   int N, int o) {
    int j = o & 7;
    int lane = (o >> 3) & 63;
    int frag = o >> 9;
    int ntiles = N >> 4;
    int nt = frag % ntiles;
    int kt = frag / ntiles;
    int k = kt * 32 + (lane >> 4) * 8 + j;
    int n = nt * 16 + (lane & 15);
    Ws[o] = (_Float16)W[k * N + n];
}

__global__ void setup_all(const int* __restrict__ idx, int* __restrict__ inv,
                          const float* sW1, const float* sW2, const float* aW1,
                          const float* aW2, const float* bW1, const float* bW2,
                          _Float16* sW1s, _Float16* sW2s, _Float16* aW1s,
                          _Float16* aW2s, _Float16* bW1s, _Float16* bW2s,
                          const int* __restrict__ ei_f, const int* __restrict__ ei_c,
                          int* __restrict__ cnt) {
    const int bb = blockIdx.x, t = threadIdx.x;
    if (bb < 64) {
        int i = bb * 256 + t;
        inv[idx[i]] = i;
    } else if (bb < 192) {
        swizzle_dev(sW1, sW1s, 128, (bb - 64) * 256 + t);
    } else if (bb < 256) {
        swizzle_dev(sW2, sW2s, 128, (bb - 192) * 256 + t);
    } else if (bb < 320) {
        swizzle_dev(aW1, aW1s, 64, (bb - 256) * 256 + t);
    } else if (bb < 336) {
        swizzle_dev(aW2, aW2s, 64, (bb - 320) * 256 + t);
    } else if (bb < 400) {
        swizzle_dev(bW1, bW1s, 128, (bb - 336) * 256 + t);
    } else if (bb < 464) {
        swizzle_dev(bW2, bW2s, 128, (bb - 400) * 256 + t);
    } else if (bb < 1488) {
        int e = (bb - 464) * 256 + t;
        atomicAdd(&cnt[ei_f[E_F + e]], 1);
    } else {
        int e = (bb - 1488) * 256 + t;
        atomicAdd(&cnt[N_F + ei_c[E_C + e]], 1);
    }
}

// ---------------- counting sort (f bins [0,N_F), c bins [N_F,N_F+N_C)) ----------------
__global__ void scan1(const int* __restrict__ cnt, int* __restrict__ csum) {
    __shared__ int red[4];
    int v = cnt[blockIdx.x * 256 + threadIdx.x];
    #pragma unroll
    for (int off = 32; off >= 1; off >>= 1) v += __shfl_xor(v, off, 64);
    if ((threadIdx.x & 63) == 0) red[threadIdx.x >> 6] = v;
    __syncthreads();
    if (threadIdx.x == 0) csum[blockIdx.x] = red[0] + red[1] + red[2] + red[3];
}

__global__ void scan2(const int* __restrict__ csum, int* __restrict__ cbase) {
    __shared__ int buf[256];
    const int t = threadIdx.x;
    int v = csum[t];
    buf[t] = v;
    __syncthreads();
    for (int off = 1; off < 256; off <<= 1) {
        int u = (t >= off) ? buf[t - off] : 0;
        __syncthreads();
        buf[t] += u;
        __syncthreads();
    }
    cbase[t] = buf[t] - v;
    __syncthreads();
    int v2 = (t < 64) ? csum[256 + t] : 0;
    buf[t] = v2;
    __syncthreads();
    for (int off = 1; off < 64; off <<= 1) {
        int u = (t >= off) ? buf[t - off] : 0;
        __syncthreads();
        buf[t] += u;
        __syncthreads();
    }
    if (t < 64) cbase[256 + t] = buf[t] - v2;
}

__global__ void scan3(const int* __restrict__ cnt, const int* __restrict__ cbase,
                      int* __restrict__ cursor) {
    __shared__ int buf[256];
    const int t = threadIdx.x, bb = blockIdx.x;
    int v = cnt[bb * 256 + t];
    buf[t] = v;
    __syncthreads();
    for (int off = 1; off < 256; off <<= 1) {
        int u = (t >= off) ? buf[t - off] : 0;
        __syncthreads();
        buf[t] += u;
        __syncthreads();
    }
    cursor[bb * 256 + t] = cbase[bb] + buf[t] - v;
}

// builds dst-sorted gather tables {si, di, dst, 0} directly
__global__ void scatter2(const int* __restrict__ ei_f, const int* __restrict__ ei_c,
                         const int* __restrict__ inv, int* __restrict__ cursor,
                         i32x4* __restrict__ gtab_f, i32x4* __restrict__ gtab_c) {
    const int bb = blockIdx.x, t = threadIdx.x;
    if (bb < 1024) {
        int e = bb * 256 + t;
        int s = ei_f[e], d = ei_f[E_F + e];
        int p = atomicAdd(&cursor[d], 1);
        i32x4 v = {inv[s], inv[d], d, 0};
        gtab_f[p] = v;
    } else {
        int e = (bb - 1024) * 256 + t;
        int s = ei_c[e], d = ei_c[E_C + e];
        int p = atomicAdd(&cursor[N_F + d], 1);
        i32x4 v = {s, d, d, 0};
        gtab_c[p] = v;
    }
}

// ---------------- barrier-free edgeconv: each wave owns 16 sorted edges ----------------
// 256 threads = 4 independent waves. Per wave: A-frags (M=16 edges) gathered straight
// from global into registers; h1 transposed through per-wave LDS (DS is in-order per
// wave -> no __syncthreads anywhere); LN + scatter from GEMM2 accs in registers.
template <int CIN, int COUT>
__launch_bounds__(256, 4) __global__
void edge_mfma(const float* __restrict__ xin, int bs_in,
               const i32x4* __restrict__ gtab, int E,
               const _Float16* __restrict__ W1s, const float* __restrict__ b1,
               const _Float16* __restrict__ W2s, const float* __restrict__ b2,
               const float* __restrict__ g, const float* __restrict__ bt,
               float* __restrict__ out, int bs_out) {
    constexpr int NC  = CIN / 32;    // k-chunks per feature half
    constexpr int NT  = COUT / 16;   // 16-col tiles (full COUT per wave)
    constexpr int KT2 = COUT / 32;
    constexpr int HPITCH = COUT + 8; // halfs; 16B-aligned rows, 2-way bank alias (free)

    __shared__ __align__(16) _Float16 h1L[4 * 16 * HPITCH];

    const int t = threadIdx.x;
    const int wv = t >> 6, lane = t & 63;
    const int q = lane >> 4, lm = lane & 15;
    _Float16* h1w = h1L + wv * 16 * HPITCH;

    const int eb = blockIdx.x * 64 + wv * 16;
    const int b = eb / E;            // E % 64 == 0 -> uniform per block
    const int e0 = eb - b * E;

    const i32x4 gt = gtab[e0 + lm];  // lane's edge = lm
    const int si = gt.x, di = gt.y, dst = gt.z;

    const float* base = xin + (size_t)b * bs_in;
    const float* prd = base + (ptrdiff_t)di * CIN;
    const float* prs = base + (ptrdiff_t)si * CIN;
    const int ko = q * 8;
    const f32x4 z4 = {0.f, 0.f, 0.f, 0.f};

    f32x4 acc[NT];
    #pragma unroll
    for (int nt = 0; nt < NT; ++nt) acc[nt] = z4;

    // ---- GEMM1 phase A: xd chunks (A built in regs from global) ----
    half8 hd[NC];
    #pragma unroll
    for (int c = 0; c < NC; ++c) {
        f32x4 d0 = z4, d1 = z4;
        if (di >= 0) {
            d0 = *(const f32x4*)(prd + c * 32 + ko);
            d1 = *(const f32x4*)(prd + c * 32 + ko + 4);
        }
        half8 h;
        #pragma unroll
        for (int j = 0; j < 4; ++j) { h[j] = (_Float16)d0[j]; h[4 + j] = (_Float16)d1[j]; }
        hd[c] = h;
        #pragma unroll
        for (int nt = 0; nt < NT; ++nt) {
            half8 bf = *(const half8*)(W1s + ((size_t)(c * NT + nt) * 64 + lane) * 8);
            acc[nt] = __builtin_amdgcn_mfma_f32_16x16x32_f16(h, bf, acc[nt], 0, 0, 0);
        }
    }
    // ---- GEMM1 phase B: (xs - xd) chunks ----
    #pragma unroll
    for (int c = 0; c < NC; ++c) {
        f32x4 s0 = z4, s1 = z4;
        if (si >= 0) {
            s0 = *(const f32x4*)(prs + c * 32 + ko);
            s1 = *(const f32x4*)(prs + c * 32 + ko + 4);
        }
        half8 h;
        #pragma unroll
        for (int j = 0; j < 4; ++j) { h[j] = (_Float16)s0[j]; h[4 + j] = (_Float16)s1[j]; }
        h = h - hd[c];
        #pragma unroll
        for (int nt = 0; nt < NT; ++nt) {
            half8 bf = *(const half8*)(W1s + ((size_t)((NC + c) * NT + nt) * 64 + lane) * 8);
            acc[nt] = __builtin_amdgcn_mfma_f32_16x16x32_f16(h, bf, acc[nt], 0, 0, 0);
        }
    }

    // ---- bias + relu -> h1 (per-wave LDS, C-layout rows = edges q*4+r) ----
    #pragma unroll
    for (int nt = 0; nt < NT; ++nt) {
        const float b1v = b1[nt * 16 + lm];
        #pragma unroll
        for (int r = 0; r < 4; ++r)
            h1w[(q * 4 + r) * HPITCH + nt * 16 + lm] =
                (_Float16)fmaxf(acc[nt][r] + b1v, 0.f);
    }

    // ---- GEMM2 (A-frags re-read from h1 in A-layout; same-wave DS ordering) ----
    f32x4 acc2[NT];
    #pragma unroll
    for (int nt = 0; nt < NT; ++nt) acc2[nt] = z4;
    #pragma unroll
    for (int kt = 0; kt < KT2; ++kt) {
        half8 a = *(const half8*)(h1w + lm * HPITCH + kt * 32 + ko);
        #pragma unroll
        for (int nt = 0; nt < NT; ++nt) {
            half8 bf = *(const half8*)(W2s + ((size_t)(kt * NT + nt) * 64 + lane) * 8);
            acc2[nt] = __builtin_amdgcn_mfma_f32_16x16x32_f16(a, bf, acc2[nt], 0, 0, 0);
        }
    }

    // ---- LN stats per row, fully in registers (reduce over 16-lane group) ----
    float b2v[NT], gv[NT], btv[NT];
    #pragma unroll
    for (int nt = 0; nt < NT; ++nt) {
        b2v[nt] = b2[nt * 16 + lm];
        gv[nt]  = g[nt * 16 + lm];
        btv[nt] = bt[nt * 16 + lm];
    }
    float sr[4] = {0.f, 0.f, 0.f, 0.f}, s2r[4] = {0.f, 0.f, 0.f, 0.f};
    #pragma unroll
    for (int nt = 0; nt < NT; ++nt)
        #pragma unroll
        for (int r = 0; r < 4; ++r) {
            float v = acc2[nt][r] + b2v[nt];
            sr[r] += v;
            s2r[r] += v * v;
        }
    #pragma unroll
    for (int off = 1; off <= 8; off <<= 1)
        #pragma unroll
        for (int r = 0; r < 4; ++r) {
            sr[r]  += __shfl_xor(sr[r], off, 64);
            s2r[r] += __shfl_xor(s2r[r], off, 64);
        }
    float mu[4], rsd[4];
    #pragma unroll
    for (int r = 0; r < 4; ++r) {
        mu[r] = sr[r] * (1.f / COUT);
        rsd[r] = rsqrtf(s2r[r] * (1.f / COUT) - mu[r] * mu[r] + 1e-5f);
    }

    // ---- apply LN + run-aggregated atomic scatter (dst-sorted rows) ----
    float rsum[NT];
    #pragma unroll
    for (int nt = 0; nt < NT; ++nt) rsum[nt] = 0.f;
    float* ob = out + (size_t)b * bs_out;
    #pragma unroll
    for (int r = 0; r < 4; ++r) {
        const int row = q * 4 + r;
        const int drow  = __shfl(dst, row, 64);
        const int dnext = __shfl(dst, (row + 1) & 15, 64);
        #pragma unroll
        for (int nt = 0; nt < NT; ++nt)
            rsum[nt] += (acc2[nt][r] + b2v[nt] - mu[r]) * rsd[r] * gv[nt] + btv[nt];
        if (r == 3 || dnext != drow) {
            float* op = ob + (size_t)drow * COUT + lm;
            #pragma unroll
            for (int nt = 0; nt < NT; ++nt) {
                atomicAdd(op + nt * 16, rsum[nt]);
                rsum[nt] = 0.f;
            }
        }
    }
}

__global__ void leaky_kernel(float* __restrict__ out, int n4) {
    int i = blockIdx.x * blockDim.x + threadIdx.x;
    if (i < n4) {
        f32x4 v = ((f32x4*)out)[i];
        #pragma unroll
        for (int c = 0; c < 4; ++c) v[c] = v[c] > 0.f ? v[c] : 0.01f * v[c];
        ((f32x4*)out)[i] = v;
    }
}

extern "C" void kernel_launch(void* const* d_in, const int* in_sizes, int n_in,
                              void* d_out, int out_size, void* d_ws, size_t ws_size,
                              hipStream_t stream) {
    const float* x    = (const float*)d_in[0];
    const int*   idx  = (const int*)d_in[1];
    const int*   ei_c = (const int*)d_in[2];
    const int*   ei_f = (const int*)d_in[3];
    const float* sW1 = (const float*)d_in[4];
    const float* sb1 = (const float*)d_in[5];
    const float* sW2 = (const float*)d_in[6];
    const float* sb2 = (const float*)d_in[7];
    const float* sg  = (const float*)d_in[8];
    const float* sbt = (const float*)d_in[9];
    const float* aW1 = (const float*)d_in[10];
    const float* ab1 = (const float*)d_in[11];
    const float* aW2 = (const float*)d_in[12];
    const float* ab2 = (const float*)d_in[13];
    const float* ag  = (const float*)d_in[14];
    const float* abt = (const float*)d_in[15];
    const float* bW1 = (const float*)d_in[16];
    const float* bb1 = (const float*)d_in[17];
    const float* bW2 = (const float*)d_in[18];
    const float* bb2 = (const float*)d_in[19];
    const float* bg  = (const float*)d_in[20];
    const float* bbt = (const float*)d_in[21];

    float* out = (float*)d_out;

    // ---- ws layout ----
    char* ws = (char*)d_ws;
    int*   inv    = (int*)ws;                                ws += (size_t)N_F * 4;
    float* h_a    = (float*)ws;                              ws += (size_t)NB * N_C * 64 * 4;
    i32x4* gtab_f = (i32x4*)ws;                              ws += (size_t)E_F * 16;
    i32x4* gtab_c = (i32x4*)ws;                              ws += (size_t)E_C * 16;
    int*   cnt    = (int*)ws;                                ws += (size_t)(N_F + N_C) * 4;
    int*   cursor = (int*)ws;                                ws += (size_t)(N_F + N_C) * 4;
    int*   csum   = (int*)ws;                                ws += 320 * 4;
    int*   cbase  = (int*)ws;                                ws += 320 * 4;
    _Float16* sW1s = (_Float16*)ws;                          ws += 256 * 128 * 2;
    _Float16* sW2s = (_Float16*)ws;                          ws += 128 * 128 * 2;
    _Float16* aW1s = (_Float16*)ws;                          ws += 256 * 64 * 2;
    _Float16* aW2s = (_Float16*)ws;                          ws += 64 * 64 * 2;
    _Float16* bW1s = (_Float16*)ws;                          ws += 128 * 128 * 2;
    _Float16* bW2s = (_Float16*)ws;                          ws += 128 * 128 * 2;

    // 1) clear: out=0, h_a=0, inv=-1, cnt=0
    clear_all<<<(int)((CLR4 + 255) / 256), 256, 0, stream>>>(out, h_a, inv, cnt);

    // 2) setup: build_inv + all weight swizzles + both dst histograms
    setup_all<<<1744, 256, 0, stream>>>(idx, inv, sW1, sW2, aW1, aW2, bW1, bW2,
                                        sW1s, sW2s, aW1s, aW2s, bW1s, bW2s,
                                        ei_f, ei_c, cnt);

    // 3-6) counting sort both edge lists by dst, emitting gather tables
    scan1<<<320, 256, 0, stream>>>(cnt, csum);
    scan2<<<1, 256, 0, stream>>>(csum, cbase);
    scan3<<<320, 256, 0, stream>>>(cnt, cbase, cursor);
    scatter2<<<1280, 256, 0, stream>>>(ei_f, ei_c, inv, cursor, gtab_f, gtab_c);

    // 7) skip = edgeconv(unpool(x), ei_f, s-params) -> out
    edge_mfma<128, 128><<<NB * E_F / 64, 256, 0, stream>>>(
        x, N_C * 128, gtab_f, E_F, sW1s, sb1, sW2s, sb2, sg, sbt, out, N_F * 128);

    // 8) h_a = edgeconv(x, ei_c, a-params)
    edge_mfma<128, 64><<<NB * E_C / 64, 256, 0, stream>>>(
        x, N_C * 128, gtab_c, E_C, aW1s, ab1, aW2s, ab2, ag, abt, h_a, N_C * 64);

    // 9) out += edgeconv(unpool(h_a), ei_f, b-params)
    edge_mfma<64, 128><<<NB * E_F / 64, 256, 0, stream>>>(
        h_a, N_C * 64, gtab_f, E_F, bW1s, bb1, bW2s, bb2, bg, bbt, out, N_F * 128);

    // 10) leaky relu in place
    leaky_kernel<<<(NB * N_F * 128 / 4 + 255) / 256, 256, 0, stream>>>(out, NB * N_F * 128 / 4);
}